// Round 1
// baseline (28.110 us; speedup 1.0000x reference)
//
#include <hip/hip_runtime.h>
#include <math.h>

// Problem constants (fixed by setup_inputs)
#define BATCH 16384
#define NCLS  1000
#define NDIM  512
#define CLS_W      1.0f
#define COLLAPSE_W 0.1f
#define COLLAPSE_EPS 5.0f

// One wave (64 lanes) per batch row; 4 waves per block.
__global__ __launch_bounds__(256) void loss_main_kernel(
    const float* __restrict__ outputs,   // [BATCH, NCLS]
    const float* __restrict__ features,  // [BATCH, NDIM]
    const float* __restrict__ means,     // [NCLS, NDIM]
    const int*   __restrict__ labels,    // [BATCH]
    float* __restrict__ partials)        // [gridDim.x * 2]  (cls_sum, col_sum)
{
    const int wave = threadIdx.x >> 6;
    const int lane = threadIdx.x & 63;
    const int row  = blockIdx.x * 4 + wave;

    // ---------------- Cross-entropy: logsumexp over NCLS=1000 ----------------
    const float* orow = outputs + (size_t)row * NCLS;
    const float4* ovec = reinterpret_cast<const float4*>(orow);

    float4 v0, v1, v2, v3;                 // 250 float4 per row; lane covers up to 4
    float mx = -INFINITY;
    {
        const float4 ninf = make_float4(-INFINITY, -INFINITY, -INFINITY, -INFINITY);
        int j0 = lane;          v0 = ovec[j0];                       // j0 < 250 always
        int j1 = lane + 64;     v1 = ovec[j1];                       // < 250 always
        int j2 = lane + 128;    v2 = ovec[j2];                       // < 250 always
        int j3 = lane + 192;    v3 = (j3 < 250) ? ovec[j3] : ninf;   // lanes 58..63 masked
        mx = fmaxf(mx, fmaxf(fmaxf(v0.x, v0.y), fmaxf(v0.z, v0.w)));
        mx = fmaxf(mx, fmaxf(fmaxf(v1.x, v1.y), fmaxf(v1.z, v1.w)));
        mx = fmaxf(mx, fmaxf(fmaxf(v2.x, v2.y), fmaxf(v2.z, v2.w)));
        mx = fmaxf(mx, fmaxf(fmaxf(v3.x, v3.y), fmaxf(v3.z, v3.w)));
    }
    #pragma unroll
    for (int off = 32; off >= 1; off >>= 1)
        mx = fmaxf(mx, __shfl_xor(mx, off));

    float s = 0.0f;
    s += __expf(v0.x - mx) + __expf(v0.y - mx) + __expf(v0.z - mx) + __expf(v0.w - mx);
    s += __expf(v1.x - mx) + __expf(v1.y - mx) + __expf(v1.z - mx) + __expf(v1.w - mx);
    s += __expf(v2.x - mx) + __expf(v2.y - mx) + __expf(v2.z - mx) + __expf(v2.w - mx);
    s += __expf(v3.x - mx) + __expf(v3.y - mx) + __expf(v3.z - mx) + __expf(v3.w - mx);
    #pragma unroll
    for (int off = 32; off >= 1; off >>= 1)
        s += __shfl_xor(s, off);

    const int lab = labels[row];
    const float lse = mx + __logf(s);
    const float cls = lse - orow[lab];      // -log p[label]

    // ---------------- Collapse: ||features[row] - means[lab]|| ----------------
    const float4* frow = reinterpret_cast<const float4*>(features + (size_t)row * NDIM);
    const float4* mrow = reinterpret_cast<const float4*>(means + (size_t)lab * NDIM);
    float ssd = 0.0f;
    {
        float4 f, m;
        f = frow[lane];      m = mrow[lane];
        float dx = f.x - m.x, dy = f.y - m.y, dz = f.z - m.z, dw = f.w - m.w;
        ssd += dx*dx + dy*dy + dz*dz + dw*dw;
        f = frow[lane + 64]; m = mrow[lane + 64];
        dx = f.x - m.x; dy = f.y - m.y; dz = f.z - m.z; dw = f.w - m.w;
        ssd += dx*dx + dy*dy + dz*dz + dw*dw;
    }
    #pragma unroll
    for (int off = 32; off >= 1; off >>= 1)
        ssd += __shfl_xor(ssd, off);
    const float col = fmaxf(COLLAPSE_EPS - sqrtf(ssd), 0.0f);

    // ---------------- Block partials (deterministic, no atomics) ----------------
    __shared__ float scl[4];
    __shared__ float sco[4];
    if (lane == 0) { scl[wave] = cls; sco[wave] = col; }
    __syncthreads();
    if (threadIdx.x == 0) {
        partials[(size_t)blockIdx.x * 2 + 0] = scl[0] + scl[1] + scl[2] + scl[3];
        partials[(size_t)blockIdx.x * 2 + 1] = sco[0] + sco[1] + sco[2] + sco[3];
    }
}

__global__ __launch_bounds__(256) void loss_final_kernel(
    const float* __restrict__ partials, int n, float* __restrict__ out)
{
    float c0 = 0.0f, c1 = 0.0f;
    for (int i = threadIdx.x; i < n; i += 256) {
        c0 += partials[(size_t)i * 2 + 0];
        c1 += partials[(size_t)i * 2 + 1];
    }
    #pragma unroll
    for (int off = 32; off >= 1; off >>= 1) {
        c0 += __shfl_xor(c0, off);
        c1 += __shfl_xor(c1, off);
    }
    __shared__ float s0[4];
    __shared__ float s1[4];
    const int wave = threadIdx.x >> 6;
    const int lane = threadIdx.x & 63;
    if (lane == 0) { s0[wave] = c0; s1[wave] = c1; }
    __syncthreads();
    if (threadIdx.x == 0) {
        const float cls_sum = s0[0] + s0[1] + s0[2] + s0[3];
        const float col_sum = s1[0] + s1[1] + s1[2] + s1[3];
        out[0] = CLS_W * (cls_sum / (float)BATCH)
               + COLLAPSE_W * (col_sum / (float)BATCH);
    }
}

extern "C" void kernel_launch(void* const* d_in, const int* in_sizes, int n_in,
                              void* d_out, int out_size, void* d_ws, size_t ws_size,
                              hipStream_t stream) {
    const float* outputs  = (const float*)d_in[0];
    const float* features = (const float*)d_in[1];
    const float* means    = (const float*)d_in[2];
    const int*   labels   = (const int*)d_in[3];
    float* out = (float*)d_out;
    float* partials = (float*)d_ws;          // 4096 * 2 floats = 32 KB

    const int nblocks = BATCH / 4;           // 4096
    loss_main_kernel<<<nblocks, 256, 0, stream>>>(outputs, features, means, labels, partials);
    loss_final_kernel<<<1, 256, 0, stream>>>(partials, nblocks, out);
}